// Round 1
// baseline (205.571 us; speedup 1.0000x reference)
//
#include <hip/hip_runtime.h>

#define NN 4096
#define IND 128
#define OUTD 64

typedef __attribute__((ext_vector_type(4))) float  floatx4;
typedef __attribute__((ext_vector_type(8))) __bf16 bf16x8;
typedef __attribute__((ext_vector_type(4))) int    intx4;

__device__ __forceinline__ unsigned short f2bf(float f) {
  unsigned int u = __float_as_uint(f);
  u += 0x7fffu + ((u >> 16) & 1u);   // RNE; inputs are finite
  return (unsigned short)(u >> 16);
}

// w_ij = (A!=0) ? exp(leaky_relu(s_i + s_j, 0.2)) : 0
__device__ __forceinline__ float wcalc(int a, float s) {
  float l = s > 0.f ? s : 0.2f * s;
  float e = __expf(l);
  return a != 0 ? e : 0.f;
}

// ---------------- Kernel 1: Wh = H@W (fp32), s_a/s_b, WhT bf16 [2][64][4096]
__global__ __launch_bounds__(256) void gat_prep(
    const float* __restrict__ H,
    const float* __restrict__ W0, const float* __restrict__ W1,
    const float* __restrict__ av0, const float* __restrict__ av1,
    unsigned short* __restrict__ whT,   // [2][64][4096] bf16 bits (c-major)
    float* __restrict__ sA,             // [2][4096]
    float* __restrict__ sB)             // [2][4096]
{
  const int rel = blockIdx.y;
  const float* __restrict__ W  = rel ? W1 : W0;
  const float* __restrict__ av = rel ? av1 : av0;
  const int i0 = blockIdx.x * 16;
  const int t = threadIdx.x;
  const int c = t & 63;                                   // lane == output channel
  const int wv = __builtin_amdgcn_readfirstlane(t >> 6);  // wave -> 4 rows
  const float* __restrict__ hp = H + (size_t)(i0 + wv * 4) * IND;

  float acc0 = 0.f, acc1 = 0.f, acc2 = 0.f, acc3 = 0.f;
#pragma unroll 8
  for (int k = 0; k < IND; k += 4) {
    float4 h0 = *(const float4*)(hp + k);
    float4 h1 = *(const float4*)(hp + IND + k);
    float4 h2 = *(const float4*)(hp + 2 * IND + k);
    float4 h3 = *(const float4*)(hp + 3 * IND + k);
    float w0 = W[(k + 0) * OUTD + c];
    float w1 = W[(k + 1) * OUTD + c];
    float w2 = W[(k + 2) * OUTD + c];
    float w3 = W[(k + 3) * OUTD + c];
    acc0 += h0.x * w0 + h0.y * w1 + h0.z * w2 + h0.w * w3;
    acc1 += h1.x * w0 + h1.y * w1 + h1.z * w2 + h1.w * w3;
    acc2 += h2.x * w0 + h2.y * w1 + h2.z * w2 + h2.w * w3;
    acc3 += h3.x * w0 + h3.y * w1 + h3.z * w2 + h3.w * w3;
  }

  // s_a = Wh . a[:64], s_b = Wh . a[64:]  (wave reduction over 64 channels)
  const float alo = av[c], ahi = av[OUTD + c];
  float pa0 = acc0 * alo, pa1 = acc1 * alo, pa2 = acc2 * alo, pa3 = acc3 * alo;
  float pb0 = acc0 * ahi, pb1 = acc1 * ahi, pb2 = acc2 * ahi, pb3 = acc3 * ahi;
#pragma unroll
  for (int off = 32; off >= 1; off >>= 1) {
    pa0 += __shfl_xor(pa0, off); pa1 += __shfl_xor(pa1, off);
    pa2 += __shfl_xor(pa2, off); pa3 += __shfl_xor(pa3, off);
    pb0 += __shfl_xor(pb0, off); pb1 += __shfl_xor(pb1, off);
    pb2 += __shfl_xor(pb2, off); pb3 += __shfl_xor(pb3, off);
  }
  const int ibase = i0 + wv * 4;
  if (c == 0) {
    float* sa = sA + rel * NN + ibase;
    float* sb = sB + rel * NN + ibase;
    sa[0] = pa0; sa[1] = pa1; sa[2] = pa2; sa[3] = pa3;
    sb[0] = pb0; sb[1] = pb1; sb[2] = pb2; sb[3] = pb3;
  }

  // WhT bf16, c-major: WhT[rel][c][i] — thread writes 4 consecutive i's (8B)
  unsigned long long packed =
      (unsigned long long)f2bf(acc0)        | ((unsigned long long)f2bf(acc1) << 16) |
      ((unsigned long long)f2bf(acc2) << 32) | ((unsigned long long)f2bf(acc3) << 48);
  *(unsigned long long*)(whT + (size_t)(rel * OUTD + c) * NN + ibase) = packed;
}

// ---------------- Kernel 2: masked-softmax matmul via MFMA, no LDS in K-loop.
// Block = (row-tile of 16, rel); 8 waves = 8 K-chunks of 512 j each.
__global__ __launch_bounds__(512) void gat_main(
    const int* __restrict__ A0, const int* __restrict__ A1,
    const unsigned short* __restrict__ whT,
    const float* __restrict__ sA, const float* __restrict__ sB,
    float* __restrict__ res)            // [2][4096][64] per-relation results
{
  __shared__ float red[8][1024];        // 32 KB numerator partials
  __shared__ float dred[8][16];         // denominator partials
  const int rel  = blockIdx.y;
  const int i0   = blockIdx.x * 16;
  const int t    = threadIdx.x;
  const int w    = t >> 6;              // K-chunk 0..7
  const int lane = t & 63;
  const int m    = lane & 15;           // output-row index within tile (A-frag m)
  const int quad = lane >> 4;           // k-slot group
  const int i    = i0 + m;
  const int* __restrict__ A = rel ? A1 : A0;
  const float si = sA[rel * NN + i];
  const float* __restrict__ sb = sB + rel * NN;
  const unsigned short* __restrict__ wh = whT + (size_t)rel * OUTD * NN;

  const int jbase = w * 512 + quad * 8;
  const int*            pA  = A  + (size_t)i * NN + jbase;
  const float*          psb = sb + jbase;
  const unsigned short* pb0 = wh + (size_t)(0 * 16 + m) * NN + jbase;
  const unsigned short* pb1 = wh + (size_t)(1 * 16 + m) * NN + jbase;
  const unsigned short* pb2 = wh + (size_t)(2 * 16 + m) * NN + jbase;
  const unsigned short* pb3 = wh + (size_t)(3 * 16 + m) * NN + jbase;

  floatx4 acc0 = {0.f, 0.f, 0.f, 0.f}, acc1 = acc0, acc2 = acc0, acc3 = acc0;
  float dsum = 0.f;

  for (int jt = 0; jt < 512; jt += 32) {
    intx4 a0 = __builtin_nontemporal_load((const intx4*)(pA + jt));      // A streams once
    intx4 a1 = __builtin_nontemporal_load((const intx4*)(pA + jt + 4));
    float4 s0 = *(const float4*)(psb + jt);
    float4 s1 = *(const float4*)(psb + jt + 4);
    bf16x8 b0 = *(const bf16x8*)(pb0 + jt);
    bf16x8 b1 = *(const bf16x8*)(pb1 + jt);
    bf16x8 b2 = *(const bf16x8*)(pb2 + jt);
    bf16x8 b3 = *(const bf16x8*)(pb3 + jt);

    float e0 = wcalc(a0[0], si + s0.x);
    float e1 = wcalc(a0[1], si + s0.y);
    float e2 = wcalc(a0[2], si + s0.z);
    float e3 = wcalc(a0[3], si + s0.w);
    float e4 = wcalc(a1[0], si + s1.x);
    float e5 = wcalc(a1[1], si + s1.y);
    float e6 = wcalc(a1[2], si + s1.z);
    float e7 = wcalc(a1[3], si + s1.w);
    dsum += ((e0 + e1) + (e2 + e3)) + ((e4 + e5) + (e6 + e7));

    bf16x8 af;
    af[0] = (__bf16)e0; af[1] = (__bf16)e1; af[2] = (__bf16)e2; af[3] = (__bf16)e3;
    af[4] = (__bf16)e4; af[5] = (__bf16)e5; af[6] = (__bf16)e6; af[7] = (__bf16)e7;

    acc0 = __builtin_amdgcn_mfma_f32_16x16x32_bf16(af, b0, acc0, 0, 0, 0);
    acc1 = __builtin_amdgcn_mfma_f32_16x16x32_bf16(af, b1, acc1, 0, 0, 0);
    acc2 = __builtin_amdgcn_mfma_f32_16x16x32_bf16(af, b2, acc2, 0, 0, 0);
    acc3 = __builtin_amdgcn_mfma_f32_16x16x32_bf16(af, b3, acc3, 0, 0, 0);
  }

  // denominator: combine the 4 quads (k-slot groups) of each row
  dsum += __shfl_xor(dsum, 16);
  dsum += __shfl_xor(dsum, 32);

  // C/D layout: col = lane&15 (+16*nt), row = quad*4 + reg   [m89/m91]
#pragma unroll
  for (int r = 0; r < 4; r++) {
    const int row = quad * 4 + r;
    red[w][row * 64 + 0 * 16 + m] = acc0[r];
    red[w][row * 64 + 1 * 16 + m] = acc1[r];
    red[w][row * 64 + 2 * 16 + m] = acc2[r];
    red[w][row * 64 + 3 * 16 + m] = acc3[r];
  }
  if (lane < 16) dred[w][lane] = dsum;
  __syncthreads();

  const int c  = t & 63;
  const int r0 = t >> 6;
#pragma unroll
  for (int rr = r0; rr < 16; rr += 8) {
    float ns = 0.f, ds = 0.f;
#pragma unroll
    for (int ww = 0; ww < 8; ww++) { ns += red[ww][rr * 64 + c]; ds += dred[ww][rr]; }
    float rv = ds > 0.f ? ns / ds : 0.f;   // isolated-row nan_to_num -> 0
    res[((size_t)rel * NN + i0 + rr) * OUTD + c] = rv;
  }
}

// ---------------- Kernel 3: out = res0 + res1 + bias
__global__ __launch_bounds__(256) void gat_combine(
    const float* __restrict__ res, const float* __restrict__ bias,
    float* __restrict__ out)
{
  const int idx = blockIdx.x * 256 + threadIdx.x;  // float4 index, 65536 total
  float4 r0 = ((const float4*)res)[idx];
  float4 r1 = ((const float4*)res)[idx + NN * OUTD / 4];
  float4 b  = ((const float4*)bias)[idx & 15];
  float4 o;
  o.x = r0.x + r1.x + b.x;
  o.y = r0.y + r1.y + b.y;
  o.z = r0.z + r1.z + b.z;
  o.w = r0.w + r1.w + b.w;
  ((float4*)out)[idx] = o;
}

extern "C" void kernel_launch(void* const* d_in, const int* in_sizes, int n_in,
                              void* d_out, int out_size, void* d_ws, size_t ws_size,
                              hipStream_t stream) {
  const float* H    = (const float*)d_in[0];
  const int*   A0   = (const int*)d_in[1];
  const int*   A1   = (const int*)d_in[2];
  const float* W0   = (const float*)d_in[3];
  const float* W1   = (const float*)d_in[4];
  const float* av0  = (const float*)d_in[5];
  const float* av1  = (const float*)d_in[6];
  const float* bias = (const float*)d_in[7];
  float* out = (float*)d_out;

  // ws layout: whT [2][64][4096] bf16 (1 MB) | sA [2][4096] | sB [2][4096] | res [2][4096][64]
  unsigned short* whT = (unsigned short*)d_ws;
  float* sA  = (float*)((char*)d_ws + 2u * OUTD * NN * 2u);
  float* sB  = sA + 2 * NN;
  float* res = sB + 2 * NN;

  gat_prep<<<dim3(NN / 16, 2), 256, 0, stream>>>(H, W0, W1, av0, av1, whT, sA, sB);
  gat_main<<<dim3(NN / 16, 2), 512, 0, stream>>>(A0, A1, whT, sA, sB, res);
  gat_combine<<<(NN * OUTD / 4) / 256, 256, 0, stream>>>(res, bias, out);
}